// Round 3
// baseline (25.202 us; speedup 1.0000x reference)
//
#include <hip/hip_runtime.h>
#include <hip/hip_bf16.h>

// out[b, 0, h, w] = min over c of x[b, T-1, c, h, w]
// x: [B=4, T=8, C=32, H=512, W=512] float32, contiguous.
// Memory-bound: read 134 MB + write 4.2 MB. Measured 5.50 TB/s (R2);
// this round: wider per-block tiles (2 x 4 KiB per channel) for fewer,
// longer DRAM read streams + 2x per-wave MLP.

typedef float f32x4 __attribute__((ext_vector_type(4)));

static __device__ __forceinline__ f32x4 vmin4(f32x4 a, f32x4 b) {
    f32x4 r;
    r[0] = fminf(a[0], b[0]);
    r[1] = fminf(a[1], b[1]);
    r[2] = fminf(a[2], b[2]);
    r[3] = fminf(a[3], b[3]);
    return r;
}

__global__ void __launch_bounds__(256)
min_last_t_kernel(const f32x4* __restrict__ x, f32x4* __restrict__ out) {
    constexpr int HW4   = (512 * 512) / 4;   // 65536 float4s per plane
    constexpr int C     = 32;
    constexpr int CHW4  = C * HW4;
    constexpr int TCHW4 = 8 * CHW4;
    constexpr int NT    = 2;                 // 4-KiB chunks per block per channel

    // Block handles NT*256 consecutive output float4s (512 = 8 KiB), all
    // within one batch image (512 divides 65536).
    int i0 = blockIdx.x * (256 * NT) + threadIdx.x;
    int b  = i0 >> 16;            // / HW4
    int p  = i0 & (HW4 - 1);      // % HW4

    const f32x4* base = x + (size_t)b * TCHW4 + (size_t)7 * CHW4 + p;

    // Stagger channel start per block: spreads instantaneous HBM traffic
    // across the whole 128 MiB footprint.
    int c0 = blockIdx.x & (C - 1);

    f32x4 m0, m1;
    {
        const f32x4* pc = base + (size_t)c0 * HW4;
        m0 = __builtin_nontemporal_load(pc);
        m1 = __builtin_nontemporal_load(pc + 256);
    }
    #pragma unroll
    for (int k = 1; k < C; ++k) {
        int c = (c0 + k) & (C - 1);
        const f32x4* pc = base + (size_t)c * HW4;
        f32x4 v0 = __builtin_nontemporal_load(pc);
        f32x4 v1 = __builtin_nontemporal_load(pc + 256);
        m0 = vmin4(m0, v0);
        m1 = vmin4(m1, v1);
    }
    __builtin_nontemporal_store(m0, out + i0);
    __builtin_nontemporal_store(m1, out + i0 + 256);
}

extern "C" void kernel_launch(void* const* d_in, const int* in_sizes, int n_in,
                              void* d_out, int out_size, void* d_ws, size_t ws_size,
                              hipStream_t stream) {
    const f32x4* x = (const f32x4*)d_in[0];
    f32x4* out = (f32x4*)d_out;

    constexpr int n4    = 4 * (512 * 512) / 4;   // 262144 output float4s
    constexpr int block = 256;
    constexpr int NT    = 2;
    constexpr int grid  = n4 / (block * NT);     // 512 blocks

    min_last_t_kernel<<<grid, block, 0, stream>>>(x, out);
}